// Round 6
// baseline (666.101 us; speedup 1.0000x reference)
//
#include <hip/hip_runtime.h>

#define BB 8
#define CH 256
#define HH 96
#define WW 192
#define HW (HH*WW)            // 18432
#define ND 25
#define NTHR 320              // 5 waves: one dy-group each

// Barrier-free correlation: no LDS, no __syncthreads, no inline asm.
// Thread = (image b, dy-group g, row r, col-quad wq): accumulates 5 dx-disps
// x 4 outputs over 256 channels. Per channel: 3 aligned float4 in2 loads
// (window [wq-4, wq+8) of row y = h+2g-4) + 1 float4 in1 load, 20 FMA.
// Cross-thread redundancy (x15 in2, x5 in1) is served by L1/L2, not HBM.
// 576 blocks = 8 XCDs x 72 tiles: bijective swizzle gives XCD x exactly
// image x -> per-channel in2 slab (74 KB) stays hot in that XCD's L2.
__global__ __launch_bounds__(NTHR, 4)
void corr_kernel(const float* __restrict__ in1, const float* __restrict__ in2,
                 float* __restrict__ out) {
  const int bid = blockIdx.x;
  const int swz = (bid & 7) * 72 + (bid >> 3);   // 576 = 8*72, bijective
  const int b   = swz / 72;                      // XCD (bid%8) -> image b
  const int rem = swz - b * 72;                  // 24 rowbands x 3 colbands
  const int h0  = (rem / 3) * 4;
  const int w0  = (rem % 3) * 64;

  const int t    = threadIdx.x;
  const int g    = t >> 6;             // dy group 0..4 (one wave each)
  const int lane = t & 63;
  const int r    = lane >> 4;          // 0..3 tile row
  const int i    = lane & 15;          // col quad index
  const int h    = h0 + r;
  const int wq   = w0 + (i << 2);
  const int y    = h + 2 * g - 4;      // in2 row for this dy-group

  const bool rowok = ((unsigned)y < HH);
  const bool lok   = rowok & (wq >= 4);
  const bool rok   = rowok & (wq <= 184);

  const size_t bpl = (size_t)b * CH * HW;
  const float* p1 = in1 + bpl + (size_t)h * WW + wq;
  const float* p2 = in2 + bpl + (size_t)(rowok ? y : 0) * WW + wq;

  const float4 z4 = make_float4(0.f, 0.f, 0.f, 0.f);
  float4 acc[5];
  #pragma unroll
  for (int j = 0; j < 5; ++j) acc[j] = z4;

  #pragma unroll 4
  for (int cc = 0; cc < CH; ++cc) {
    const float4 a  = *(const float4*)p1;
    const float4 wl = lok   ? *(const float4*)(p2 - 4) : z4;
    const float4 wm = rowok ? *(const float4*)(p2)     : z4;
    const float4 wr = rok   ? *(const float4*)(p2 + 4) : z4;
    float wv[12];
    wv[0] = wl.x; wv[1]  = wl.y; wv[2]  = wl.z; wv[3]  = wl.w;
    wv[4] = wm.x; wv[5]  = wm.y; wv[6]  = wm.z; wv[7]  = wm.w;
    wv[8] = wr.x; wv[9]  = wr.y; wv[10] = wr.z; wv[11] = wr.w;
    #pragma unroll
    for (int j = 0; j < 5; ++j) {
      float4& A = acc[j];
      A.x = fmaf(a.x, wv[0 + 2*j], A.x);
      A.y = fmaf(a.y, wv[1 + 2*j], A.y);
      A.z = fmaf(a.z, wv[2 + 2*j], A.z);
      A.w = fmaf(a.w, wv[3 + 2*j], A.w);
    }
    p1 += HW;
    p2 += HW;
  }

  // Direct final output, coalesced float4 per disp (d = 5g + j).
  const float scale = 1.0f / CH;
  float* pout = out + ((size_t)(b * ND + g * 5) * HH + h) * WW + wq;
  #pragma unroll
  for (int j = 0; j < 5; ++j) {
    float4 v;
    v.x = acc[j].x * scale; v.y = acc[j].y * scale;
    v.z = acc[j].z * scale; v.w = acc[j].w * scale;
    *(float4*)(pout + (size_t)j * HW) = v;
  }
}

extern "C" void kernel_launch(void* const* d_in, const int* in_sizes, int n_in,
                              void* d_out, int out_size, void* d_ws, size_t ws_size,
                              hipStream_t stream) {
  const float* in1 = (const float*)d_in[0];
  const float* in2 = (const float*)d_in[1];
  float* out = (float*)d_out;
  corr_kernel<<<dim3(BB * 72), NTHR, 0, stream>>>(in1, in2, out);
}

// Round 7
// 188.664 us; speedup vs baseline: 3.5306x; 3.5306x over previous
//
#include <hip/hip_runtime.h>

#define BB 8
#define CH 256
#define HH 96
#define WW 192
#define HW (HH*WW)            // 18432
#define ND 25
#define NTHR 320              // 5 waves: one dy-group each
#define UNR 4                 // channels per load batch

// Barrier-free correlation, branch-free loads.
// Thread = (image b, dy-group g, row r, col-quad wq): 5 dx-disps x 4 outputs
// over 256 channels. All loads are UNCONDITIONAL from clamped addresses
// (row clamped to [0,95]; left/right quad offsets applied only when valid,
// else aliased to the middle quad) and the values are zeroed by cndmask.
// No exec-mask branches -> the 16-load batch per UNR=4 channels stays
// parallel in flight. No LDS, no barriers; redundancy served by L1/L2.
__global__ __launch_bounds__(NTHR, 4)
void corr_kernel(const float* __restrict__ in1, const float* __restrict__ in2,
                 float* __restrict__ out) {
  const int bid = blockIdx.x;
  const int swz = (bid & 7) * 72 + (bid >> 3);   // 576 = 8*72, bijective
  const int b   = swz / 72;                      // XCD (bid%8) -> image b
  const int rem = swz - b * 72;                  // 24 rowbands x 3 colbands
  const int h0  = (rem / 3) * 4;
  const int w0  = (rem % 3) * 64;

  const int t    = threadIdx.x;
  const int g    = t >> 6;             // dy group 0..4 (one wave each)
  const int lane = t & 63;
  const int r    = lane >> 4;          // 0..3 tile row
  const int i    = lane & 15;          // col quad index
  const int h    = h0 + r;
  const int wq   = w0 + (i << 2);
  const int y    = h + 2 * g - 4;      // in2 row for this dy-group

  const bool rowok = ((unsigned)y < HH);
  const bool lok   = rowok && (wq >= 4);
  const bool rok   = rowok && (wq <= WW - 8);
  const int  yc    = y < 0 ? 0 : (y > HH - 1 ? HH - 1 : y);  // clamped row

  const size_t bpl = (size_t)b * CH * HW;
  const float* p1 = in1 + bpl + (size_t)h * WW + wq;
  const float* pm = in2 + bpl + (size_t)yc * WW + wq;
  const float* pl = pm - (lok ? 4 : 0);   // in-row alias when invalid
  const float* pr = pm + (rok ? 4 : 0);

  const float4 z4 = make_float4(0.f, 0.f, 0.f, 0.f);
  float4 acc[5];
  #pragma unroll
  for (int j = 0; j < 5; ++j) acc[j] = z4;

  for (int base = 0; base < CH; base += UNR) {
    // ---- batch: issue all 4*UNR loads before any use ----
    float4 A[UNR], WL[UNR], WM[UNR], WR[UNR];
    #pragma unroll
    for (int u = 0; u < UNR; ++u) {
      const size_t adv = (size_t)u * HW;
      A[u]  = *(const float4*)(p1 + adv);
      WL[u] = *(const float4*)(pl + adv);
      WM[u] = *(const float4*)(pm + adv);
      WR[u] = *(const float4*)(pr + adv);
    }
    // ---- compute ----
    #pragma unroll
    for (int u = 0; u < UNR; ++u) {
      float wv[12];
      wv[0]  = lok   ? WL[u].x : 0.f;
      wv[1]  = lok   ? WL[u].y : 0.f;
      wv[2]  = lok   ? WL[u].z : 0.f;
      wv[3]  = lok   ? WL[u].w : 0.f;
      wv[4]  = rowok ? WM[u].x : 0.f;
      wv[5]  = rowok ? WM[u].y : 0.f;
      wv[6]  = rowok ? WM[u].z : 0.f;
      wv[7]  = rowok ? WM[u].w : 0.f;
      wv[8]  = rok   ? WR[u].x : 0.f;
      wv[9]  = rok   ? WR[u].y : 0.f;
      wv[10] = rok   ? WR[u].z : 0.f;
      wv[11] = rok   ? WR[u].w : 0.f;
      const float4 a = A[u];
      #pragma unroll
      for (int j = 0; j < 5; ++j) {
        float4& Ac = acc[j];
        Ac.x = fmaf(a.x, wv[0 + 2*j], Ac.x);
        Ac.y = fmaf(a.y, wv[1 + 2*j], Ac.y);
        Ac.z = fmaf(a.z, wv[2 + 2*j], Ac.z);
        Ac.w = fmaf(a.w, wv[3 + 2*j], Ac.w);
      }
    }
    p1 += (size_t)UNR * HW;
    pl += (size_t)UNR * HW;
    pm += (size_t)UNR * HW;
    pr += (size_t)UNR * HW;
  }

  // Direct final output, coalesced float4 per disp (d = 5g + j).
  const float scale = 1.0f / CH;
  float* pout = out + ((size_t)(b * ND + g * 5) * HH + h) * WW + wq;
  #pragma unroll
  for (int j = 0; j < 5; ++j) {
    float4 v;
    v.x = acc[j].x * scale; v.y = acc[j].y * scale;
    v.z = acc[j].z * scale; v.w = acc[j].w * scale;
    *(float4*)(pout + (size_t)j * HW) = v;
  }
}

extern "C" void kernel_launch(void* const* d_in, const int* in_sizes, int n_in,
                              void* d_out, int out_size, void* d_ws, size_t ws_size,
                              hipStream_t stream) {
  const float* in1 = (const float*)d_in[0];
  const float* in2 = (const float*)d_in[1];
  float* out = (float*)d_out;
  corr_kernel<<<dim3(BB * 72), NTHR, 0, stream>>>(in1, in2, out);
}

// Round 8
// 172.956 us; speedup vs baseline: 3.8513x; 1.0908x over previous
//
#include <hip/hip_runtime.h>

#define BB 8
#define CH 256
#define HH 96
#define WW 192
#define HW (HH*WW)            // 18432
#define ND 25
#define NTHR 320              // 5 waves: one dy-group each
#define UNR 4                 // channels per pinned load batch
#define OUTSZ (BB*ND*HH*WW)   // 3686400

// Barrier-free correlation, pinned load batches, zero-page padding.
// Thread = (image b, dy-group dg, row r, col-quad wq): 5 dx-disps x 4 outputs
// over cCount channels (blockIdx.y = channel group). Per channel: 3 float4
// in2 loads + 1 float4 in1 load, ALL unconditional: invalid window quads
// read a zeroed 256B slab in d_ws with advance-stride 0 (zero padding for
// free, no per-channel cndmask). sched_barrier(0) pins each 16-load batch
// to issue before its compute -> real memory-level parallelism.
__global__ __launch_bounds__(NTHR, 4)
void corr_partial(const float* __restrict__ in1, const float* __restrict__ in2,
                  const float* __restrict__ zp, float* __restrict__ part,
                  int cCount) {
  const int bid = blockIdx.x;
  const int swz = (bid & 7) * 72 + (bid >> 3);   // 576 = 8*72, bijective
  const int b   = swz / 72;                      // XCD (bid%8) -> image b
  const int rem = swz - b * 72;                  // 24 rowbands x 3 colbands
  const int h0  = (rem / 3) * 4;
  const int w0  = (rem % 3) * 64;

  const int t    = threadIdx.x;
  const int dg   = t >> 6;             // dy group 0..4 (one wave each)
  const int lane = t & 63;
  const int r    = lane >> 4;          // 0..3 tile row
  const int i    = lane & 15;          // col quad index
  const int h    = h0 + r;
  const int wq   = w0 + (i << 2);
  const int y    = h + 2 * dg - 4;     // in2 row for this dy-group

  const bool rowok = ((unsigned)y < HH);
  const bool lok   = rowok && (wq >= 4);
  const bool rok   = rowok && (wq <= WW - 8);

  const int cBegin = blockIdx.y * cCount;
  const size_t bpl = (size_t)b * CH * HW + (size_t)cBegin * HW;

  const float* p1 = in1 + bpl + (size_t)h * WW + wq;
  const float* pm = rowok ? in2 + bpl + (size_t)y * WW + wq : zp;
  const float* pl = lok ? pm - 4 : zp;
  const float* pr = rok ? pm + 4 : zp;
  const size_t sm = rowok ? (size_t)HW : 0;      // advance strides
  const size_t sl = lok   ? (size_t)HW : 0;
  const size_t sr = rok   ? (size_t)HW : 0;

  float4 acc[5];
  #pragma unroll
  for (int j = 0; j < 5; ++j) acc[j] = make_float4(0.f, 0.f, 0.f, 0.f);

  #pragma unroll 1
  for (int base = 0; base < cCount; base += UNR) {
    // ---- issue all 16 loads; sched_barrier pins them before compute ----
    float4 A[UNR], WL[UNR], WM[UNR], WR[UNR];
    #pragma unroll
    for (int u = 0; u < UNR; ++u) {
      A[u]  = *(const float4*)(p1 + (size_t)u * HW);
      WL[u] = *(const float4*)(pl + (size_t)u * sl);
      WM[u] = *(const float4*)(pm + (size_t)u * sm);
      WR[u] = *(const float4*)(pr + (size_t)u * sr);
    }
    __builtin_amdgcn_sched_barrier(0);
    // ---- compute ----
    #pragma unroll
    for (int u = 0; u < UNR; ++u) {
      const float wv[12] = { WL[u].x, WL[u].y, WL[u].z, WL[u].w,
                             WM[u].x, WM[u].y, WM[u].z, WM[u].w,
                             WR[u].x, WR[u].y, WR[u].z, WR[u].w };
      const float4 a = A[u];
      #pragma unroll
      for (int j = 0; j < 5; ++j) {
        float4& Ac = acc[j];
        Ac.x = fmaf(a.x, wv[0 + 2*j], Ac.x);
        Ac.y = fmaf(a.y, wv[1 + 2*j], Ac.y);
        Ac.z = fmaf(a.z, wv[2 + 2*j], Ac.z);
        Ac.w = fmaf(a.w, wv[3 + 2*j], Ac.w);
      }
    }
    p1 += (size_t)UNR * HW;
    pl += (size_t)UNR * sl;
    pm += (size_t)UNR * sm;
    pr += (size_t)UNR * sr;
  }

  // Scaled partial write, coalesced float4 per disp (d = 5*dg + j).
  const float scale = 1.0f / CH;
  float* pout = part + (size_t)blockIdx.y * OUTSZ
              + ((size_t)(b * ND + dg * 5) * HH + h) * WW + wq;
  #pragma unroll
  for (int j = 0; j < 5; ++j) {
    float4 v;
    v.x = acc[j].x * scale; v.y = acc[j].y * scale;
    v.z = acc[j].z * scale; v.w = acc[j].w * scale;
    *(float4*)(pout + (size_t)j * HW) = v;
  }
}

__global__ void corr_reduce(const float* __restrict__ part,
                            float* __restrict__ out, int G) {
  const int n4 = OUTSZ / 4;
  int i = blockIdx.x * 256 + threadIdx.x;
  if (i >= n4) return;
  const float4* p = (const float4*)part;
  float4 s = p[i];
  for (int g = 1; g < G; ++g) {
    float4 v = p[(size_t)g * n4 + i];
    s.x += v.x; s.y += v.y; s.z += v.z; s.w += v.w;
  }
  ((float4*)out)[i] = s;
}

extern "C" void kernel_launch(void* const* d_in, const int* in_sizes, int n_in,
                              void* d_out, int out_size, void* d_ws, size_t ws_size,
                              hipStream_t stream) {
  const float* in1 = (const float*)d_in[0];
  const float* in2 = (const float*)d_in[1];
  float* out = (float*)d_out;

  int G = 4;  // channel groups; degrade if workspace is small
  while (G > 1 && ws_size < (size_t)G * OUTSZ * sizeof(float) + 256) G >>= 1;
  float* part = (G == 1) ? out : (float*)d_ws;
  float* zp = (float*)((char*)d_ws +
                       ((G == 1) ? 0 : (size_t)G * OUTSZ * sizeof(float)));
  hipMemsetAsync(zp, 0, 256, stream);  // zero page for padded loads

  dim3 grid(BB * 72, G);
  corr_partial<<<grid, NTHR, 0, stream>>>(in1, in2, zp, part, CH / G);
  if (G > 1) {
    corr_reduce<<<(OUTSZ/4 + 255)/256, 256, 0, stream>>>((const float*)d_ws, out, G);
  }
}